// Round 16
// baseline (290.822 us; speedup 1.0000x reference)
//
#include <hip/hip_runtime.h>
#include <hip/hip_bf16.h>
#include <hip/hip_fp16.h>
#include <math.h>

#define B_ 4
#define N_ 8192
#define K_ 16
#define BN_ (B_ * N_)
#define EPS_ 1e-5f

#define KW_ 8                 // waves per knn block
#define KT_ (KW_ * 64)        // 512 threads
#define MCAND (N_ / KW_)      // 1024 candidates per wave slice
#define DEPTH 16              // deferred-insert buffer depth

#define NBLK 512              // tail grid
#define ROWS 64               // rows per tail block (8 threads/row)

#define KEY_SENTINEL 0x7F800000FFFFFFFFULL   // (+inf distance, max idx)

// ---------------- pack coords (B*N,3) -> float4 ----------------
__global__ __launch_bounds__(256) void pack_coords(const float* __restrict__ coords,
                                                   float4* __restrict__ out) {
    int i = blockIdx.x * 256 + threadIdx.x;
    if (i >= BN_) return;
    out[i] = make_float4(coords[3 * i], coords[3 * i + 1], coords[3 * i + 2], 0.0f);
}

// ---------------- feats fp32 -> fp16 ----------------
__global__ __launch_bounds__(256) void feats2h(const float* __restrict__ in,
                                               __half* __restrict__ outh) {
    int i = blockIdx.x * 256 + threadIdx.x;
    const float4* p = (const float4*)(in + (size_t)i * 8);
    float4 a = p[0], b = p[1];
    __half2 h0; h0.x = __float2half_rn(a.x); h0.y = __float2half_rn(a.y);
    __half2 h1; h1.x = __float2half_rn(a.z); h1.y = __float2half_rn(a.w);
    __half2 h2; h2.x = __float2half_rn(b.x); h2.y = __float2half_rn(b.y);
    __half2 h3; h3.x = __float2half_rn(b.z); h3.y = __float2half_rn(b.w);
    uint4 o;
    o.x = *(unsigned*)&h0; o.y = *(unsigned*)&h1; o.z = *(unsigned*)&h2; o.w = *(unsigned*)&h3;
    ((uint4*)outh)[i] = o;
}

// ---------------- exact 16-NN: two-phase select, REGISTER histogram ----------------
// r15's structure (lane = query, wave w scans contiguous slice with wave-uniform
// s_load broadcast), but phase 1's histogram lives in ONE u64 register: 8 buckets
// x u8 fields, bucket = clamp((exp(d2)-118)>>1, 0, 7), acc += 1<<(bk*8).
// Pure VALU, 1-cycle dep chain, zero LDS (r15's 16.8M bank conflicts + rmw
// serialization eliminated). u8 wrap is conservative-safe: wrap only lowers
// reported counts -> looser T -> still exact. Cross-wave merge: 8 u64s via LDS
// once, summed field-wise after even/odd 8->16-bit spread (max 8*255 < 2^16).
// T = upper d2 edge of bucket B where cumulative count reaches 16 (B=7 -> inf).
// PHASE 2 rescans pushing only d2 < T. Keys (d2<<32)|idx -> deterministic.
__global__ __launch_bounds__(KT_) void knn_reg(const float4* __restrict__ coords4,
                                               int* __restrict__ idxOut) {
    __shared__ unsigned long long bufp[DEPTH][KT_];    // 64 KB
    __shared__ unsigned long long accs[KW_][64];       // 4 KB

    int t = threadIdx.x;
    int lane = t & 63;
    int w = __builtin_amdgcn_readfirstlane(t >> 6);
    int b = blockIdx.x >> 7;
    int g = blockIdx.x & 127;

    const float4* cb = coords4 + (size_t)b * N_;
    int q = g * 64 + lane;
    float4 qc = cb[q];
    float qx = qc.x, qy = qc.y, qz = qc.z;

    const int base = w * MCAND;

    // ---- phase 1: register histogram over own slice
    unsigned long long acc = 0;
    for (int i = 0; i < MCAND; i += 8) {
        float4 c0 = cb[base + i + 0];
        float4 c1 = cb[base + i + 1];
        float4 c2 = cb[base + i + 2];
        float4 c3 = cb[base + i + 3];
        float4 c4 = cb[base + i + 4];
        float4 c5 = cb[base + i + 5];
        float4 c6 = cb[base + i + 6];
        float4 c7 = cb[base + i + 7];
#define H1(cv)                                                         \
        {                                                              \
            float dx = qx - cv.x, dy = qy - cv.y, dz = qz - cv.z;      \
            float d2 = dx * dx;                                        \
            d2 = fmaf(dy, dy, d2);                                     \
            d2 = fmaf(dz, dz, d2);                                     \
            int e = (int)(__float_as_uint(d2) >> 23);                  \
            int bk = (e - 118) >> 1;                                   \
            bk = bk < 0 ? 0 : (bk > 7 ? 7 : bk);                       \
            acc += 1ULL << (bk << 3);                                  \
        }
        H1(c0) H1(c1) H1(c2) H1(c3) H1(c4) H1(c5) H1(c6) H1(c7)
#undef H1
    }
    accs[w][lane] = acc;
    __syncthreads();

    // ---- per-query threshold from cross-wave cumulative histogram
    float T;
    {
        const unsigned long long M8 = 0x00FF00FF00FF00FFULL;
        unsigned long long se = 0, so = 0;   // 16-bit fields: buckets 0,2,4,6 / 1,3,5,7
#pragma unroll
        for (int ww = 0; ww < KW_; ++ww) {
            unsigned long long a = accs[ww][lane];
            se += a & M8;
            so += (a >> 8) & M8;
        }
        int cum = 0;
        int B = 8;
#pragma unroll
        for (int bb = 0; bb < 8; ++bb) {
            unsigned long long s = (bb & 1) ? so : se;
            int c = (int)((s >> ((bb >> 1) << 4)) & 0xFFFF);
            cum += c;
            if (cum >= K_ && B == 8) B = bb;
        }
        // bucket bb holds exponents {118+2bb, 118+2bb+1}; upper edge = 2^(118+2bb+2-127)
        T = (B >= 7) ? 3.4e38f : __uint_as_float((unsigned)(118 + 2 * B + 2) << 23);
    }

    // ---- phase 2: rescan, push only d2 < limf (starts at T)
    unsigned long long key[K_];
#pragma unroll
    for (int j = 0; j < K_; j++) key[j] = KEY_SENTINEL;

    int cnt = 0;
    float limf = T;

    auto flush = [&]() {
        for (int j = 0; j < cnt; ++j) {
            unsigned long long e = bufp[j][t];
            if (e < key[K_ - 1]) {
#pragma unroll
                for (int jj = K_ - 1; jj > 0; --jj) {
                    bool up = e < key[jj - 1];
                    unsigned long long lo = (e < key[jj]) ? e : key[jj];
                    key[jj] = up ? key[jj - 1] : lo;
                }
                if (e < key[0]) key[0] = e;
            }
        }
        cnt = 0;
        float own = __uint_as_float((unsigned)(key[K_ - 1] >> 32));
        limf = fminf(own, T);
    };

    for (int i = 0; i < MCAND; i += 8) {
        float4 c0 = cb[base + i + 0];
        float4 c1 = cb[base + i + 1];
        float4 c2 = cb[base + i + 2];
        float4 c3 = cb[base + i + 3];
        float4 c4 = cb[base + i + 4];
        float4 c5 = cb[base + i + 5];
        float4 c6 = cb[base + i + 6];
        float4 c7 = cb[base + i + 7];
#define P2(cv, mm)                                                     \
        {                                                              \
            float dx = qx - cv.x, dy = qy - cv.y, dz = qz - cv.z;      \
            float d2 = dx * dx;                                        \
            d2 = fmaf(dy, dy, d2);                                     \
            d2 = fmaf(dz, dz, d2);                                     \
            if (d2 < limf) {                                           \
                bufp[cnt][t] = ((unsigned long long)__float_as_uint(d2) << 32) | \
                               (unsigned)(mm);                         \
                cnt++;                                                 \
            }                                                          \
        }
        P2(c0, base + i + 0) P2(c1, base + i + 1) P2(c2, base + i + 2) P2(c3, base + i + 3)
        P2(c4, base + i + 4) P2(c5, base + i + 5) P2(c6, base + i + 6) P2(c7, base + i + 7)
#undef P2
        // each lane pushed at most 8 since last check; DEPTH-7 guard => no overflow
        if (__any(cnt >= DEPTH - 7)) flush();
    }
    flush();

    // ---- publish sorted lists; tree-merge 8 -> 1 per query
#pragma unroll
    for (int j = 0; j < K_; j++) bufp[j][t] = key[j];

    int* op = idxOut + ((size_t)b * N_ + q) * K_;
    for (int step = 1; step < KW_; step <<= 1) {
        bool active = (w & (2 * step - 1)) == 0;
        unsigned long long md[K_];
        __syncthreads();
        if (active) {
            int pa = t, pb = t + step * 64;
            int ia = 0, ib = 0;
#pragma unroll
            for (int r2 = 0; r2 < K_; ++r2) {
                unsigned long long ea = bufp[ia][pa];
                unsigned long long eb = bufp[ib][pb];
                bool sel = ea <= eb;
                md[r2] = sel ? ea : eb;
                ia += sel ? 1 : 0;
                ib += sel ? 0 : 1;
            }
        }
        __syncthreads();
        if (active) {
            if (step == KW_ / 2) {
#pragma unroll
                for (int r2 = 0; r2 < K_; ++r2) op[r2] = (int)(md[r2] & 0xFFFFFFFFu);
            } else {
#pragma unroll
                for (int r2 = 0; r2 < K_; ++r2) bufp[r2][t] = md[r2];
            }
        }
    }
}

// ---------------- A: fp16 gather (XCD-swizzled) + mean + mm1 + part1 ----------------
__global__ __launch_bounds__(512) void g1_kernel(const __half* __restrict__ fh,
                                                 const int* __restrict__ idx,
                                                 const float* __restrict__ W1,
                                                 const float* __restrict__ b1,
                                                 float* __restrict__ Y1,
                                                 float* __restrict__ part1) {
    __shared__ float buf[ROWS][65];
    int t = threadIdx.x;
    int rl = t & 63;
    int h2 = __builtin_amdgcn_readfirstlane(t >> 6);
    int vbid = ((blockIdx.x & 7) << 6) + (blockIdx.x >> 3);   // XCD-contiguous
    int row = vbid * ROWS + rl;
    int bb = row >> 13;

    const __half* fb = fh + ((size_t)bb << 13) * 64;
    const int* ip = idx + (size_t)row * K_;

    float xh[8];
#pragma unroll
    for (int j = 0; j < 8; j++) xh[j] = 0.0f;
#pragma unroll
    for (int j = 0; j < K_; j++) {
        uint4 a = *(const uint4*)(fb + (((size_t)ip[j]) << 6) + h2 * 8);
        __half2* hp = (__half2*)&a;
#pragma unroll
        for (int p = 0; p < 4; p++) {
            float2 f = __half22float2(hp[p]);
            xh[2 * p] += f.x;
            xh[2 * p + 1] += f.y;
        }
    }
#pragma unroll
    for (int j = 0; j < 8; j++) buf[rl][h2 * 8 + j] = xh[j] * (1.0f / 16.0f);
    __syncthreads();

    float acc[8];
#pragma unroll
    for (int j = 0; j < 8; j++) acc[j] = b1[h2 * 8 + j];
#pragma unroll 1
    for (int c0 = 0; c0 < 64; c0 += 16) {
        float xr[16];
#pragma unroll
        for (int j = 0; j < 16; j++) xr[j] = buf[rl][c0 + j];
#pragma unroll
        for (int cc = 0; cc < 16; cc++) {
            float xv = xr[cc];
            const float* wr = W1 + (c0 + cc) * 64 + h2 * 8;
#pragma unroll
            for (int j = 0; j < 8; j++) acc[j] = fmaf(xv, wr[j], acc[j]);
        }
    }
    float2* yp = (float2*)(Y1 + (size_t)row * 64 + h2 * 8);
#pragma unroll
    for (int f = 0; f < 4; f++) yp[f] = make_float2(acc[2 * f], acc[2 * f + 1]);
    __syncthreads();
#pragma unroll
    for (int j = 0; j < 8; j++) buf[rl][h2 * 8 + j] = acc[j];
    __syncthreads();
    if (t < 128) {
        int c = t & 63;
        float s = 0.0f;
        if (t < 64) { for (int r = 0; r < ROWS; ++r) s += buf[r][c]; }
        else        { for (int r = 0; r < ROWS; ++r) { float v = buf[r][c]; s = fmaf(v, v, s); } }
        part1[blockIdx.x * 128 + t] = s;
    }
}

// ---------------- shared: reduce [NBLK][128] partials -> scs/shs (64 ch) ----------------
__device__ __forceinline__ void reduce_stats64(const float* __restrict__ part,
                                               const float* __restrict__ gma,
                                               const float* __restrict__ bta,
                                               float* red4, float* scs, float* shs) {
    int t = threadIdx.x;
    {
        int c = t & 127;
        int q = t >> 7;
        float s = 0.0f;
#pragma unroll 8
        for (int g = q * 128; g < q * 128 + 128; ++g) s += part[(size_t)g * 128 + c];
        red4[t] = s;
    }
    __syncthreads();
    if (t < 128) red4[t] = red4[t] + red4[t + 128] + red4[t + 256] + red4[t + 384];
    __syncthreads();
    if (t < 64) {
        float mean = red4[t] * (1.0f / BN_);
        float var = red4[t + 64] * (1.0f / BN_) - mean * mean;
        float rstd = rsqrtf(var + EPS_);
        float scl = rstd * gma[t];
        scs[t] = scl;
        shs[t] = bta[t] - mean * scl;
    }
    __syncthreads();
}

// ---------------- B: stats1 + bn1/relu -> x1, mm2 -> y2 + part2 ----------------
__global__ __launch_bounds__(512) void m2_kernel(const float* __restrict__ Y1,
                                                 const float* __restrict__ Wa,
                                                 const float* __restrict__ ba,
                                                 const float* __restrict__ g1,
                                                 const float* __restrict__ be1,
                                                 const float* __restrict__ part1,
                                                 float* __restrict__ X1,
                                                 float* __restrict__ Y2,
                                                 float* __restrict__ part2) {
    __shared__ float buf[ROWS][65];
    __shared__ float red4[512];
    __shared__ float scs[64], shs[64];
    int t = threadIdx.x;
    int rl = t & 63;
    int h2 = __builtin_amdgcn_readfirstlane(t >> 6);
    int row = blockIdx.x * ROWS + rl;

    reduce_stats64(part1, g1, be1, red4, scs, shs);

    const float2* y1p = (const float2*)(Y1 + (size_t)row * 64 + h2 * 8);
    float2* x1p = (float2*)(X1 + (size_t)row * 64 + h2 * 8);
#pragma unroll
    for (int f = 0; f < 4; f++) {
        float2 v = y1p[f];
        int c0 = h2 * 8 + 2 * f;
        float a = fmaxf(0.0f, fmaf(v.x, scs[c0], shs[c0]));
        float b = fmaxf(0.0f, fmaf(v.y, scs[c0 + 1], shs[c0 + 1]));
        x1p[f] = make_float2(a, b);
        buf[rl][c0] = a;
        buf[rl][c0 + 1] = b;
    }
    __syncthreads();

    float acc[8];
#pragma unroll
    for (int j = 0; j < 8; j++) acc[j] = ba[h2 * 8 + j];
#pragma unroll 1
    for (int c0 = 0; c0 < 64; c0 += 16) {
        float xr[16];
#pragma unroll
        for (int j = 0; j < 16; j++) xr[j] = buf[rl][c0 + j];
#pragma unroll
        for (int cc = 0; cc < 16; cc++) {
            float xv = xr[cc];
            const float* wr = Wa + (c0 + cc) * 64 + h2 * 8;
#pragma unroll
            for (int j = 0; j < 8; j++) acc[j] = fmaf(xv, wr[j], acc[j]);
        }
    }
    float2* y2p = (float2*)(Y2 + (size_t)row * 64 + h2 * 8);
#pragma unroll
    for (int f = 0; f < 4; f++) y2p[f] = make_float2(acc[2 * f], acc[2 * f + 1]);
    __syncthreads();
#pragma unroll
    for (int j = 0; j < 8; j++) buf[rl][h2 * 8 + j] = acc[j];
    __syncthreads();
    if (t < 128) {
        int c = t & 63;
        float s = 0.0f;
        if (t < 64) { for (int r = 0; r < ROWS; ++r) s += buf[r][c]; }
        else        { for (int r = 0; r < ROWS; ++r) { float v = buf[r][c]; s = fmaf(v, v, s); } }
        part2[blockIdx.x * 128 + t] = s;
    }
}

// ---------------- C: stats2 + attn + fused, mm3 -> y3(unnorm) + part3 ----------------
__global__ __launch_bounds__(512) void m3_kernel(const float* __restrict__ Y2,
                                                 const float* __restrict__ X1,
                                                 const float* __restrict__ W2,
                                                 const float* __restrict__ b2,
                                                 const float* __restrict__ ga,
                                                 const float* __restrict__ bea,
                                                 const float* __restrict__ part2,
                                                 float* __restrict__ Y3,
                                                 float* __restrict__ part3) {
    __shared__ float buf[ROWS][65];
    __shared__ float red4[512];
    __shared__ float scs[64], shs[64];
    int t = threadIdx.x;
    int rl = t & 63;
    int h2 = __builtin_amdgcn_readfirstlane(t >> 6);
    int row = blockIdx.x * ROWS + rl;

    reduce_stats64(part2, ga, bea, red4, scs, shs);

    const float2* y2p = (const float2*)(Y2 + (size_t)row * 64 + h2 * 8);
    const float2* x1p = (const float2*)(X1 + (size_t)row * 64 + h2 * 8);
#pragma unroll
    for (int f = 0; f < 4; f++) {
        float2 v = y2p[f];
        float2 u = x1p[f];
        int c0 = h2 * 8 + 2 * f;
        float t0 = fmaxf(0.0f, fmaf(v.x, scs[c0], shs[c0]));
        float t1 = fmaxf(0.0f, fmaf(v.y, scs[c0 + 1], shs[c0 + 1]));
        float a0 = 1.0f / (1.0f + __expf(-t0));
        float a1 = 1.0f / (1.0f + __expf(-t1));
        buf[rl][c0] = u.x * (1.0f + a0);
        buf[rl][c0 + 1] = u.y * (1.0f + a1);
    }
    __syncthreads();

    float acc16[16];
#pragma unroll
    for (int j = 0; j < 16; j++) acc16[j] = b2[h2 * 16 + j];
#pragma unroll 1
    for (int c0 = 0; c0 < 64; c0 += 16) {
        float xr[16];
#pragma unroll
        for (int j = 0; j < 16; j++) xr[j] = buf[rl][c0 + j];
#pragma unroll
        for (int cc = 0; cc < 16; cc++) {
            float xv = xr[cc];
            const float* wr = W2 + (c0 + cc) * 128 + h2 * 16;
#pragma unroll
            for (int j = 0; j < 16; j++) acc16[j] = fmaf(xv, wr[j], acc16[j]);
        }
    }
    float4* yp = (float4*)(Y3 + (size_t)row * 128 + h2 * 16);
#pragma unroll
    for (int f = 0; f < 4; f++)
        yp[f] = make_float4(acc16[4 * f], acc16[4 * f + 1], acc16[4 * f + 2], acc16[4 * f + 3]);

    __syncthreads();
    if (h2 < 4) {
#pragma unroll
        for (int j = 0; j < 16; j++) buf[rl][h2 * 16 + j] = acc16[j];
    }
    __syncthreads();
    if (t < 128) {
        int c = t & 63;
        float s = 0.0f;
        if (t < 64) { for (int r = 0; r < ROWS; ++r) s += buf[r][c]; }
        else        { for (int r = 0; r < ROWS; ++r) { float v = buf[r][c]; s = fmaf(v, v, s); } }
        part3[blockIdx.x * 256 + t] = s;
    }
    __syncthreads();
    if (h2 >= 4) {
#pragma unroll
        for (int j = 0; j < 16; j++) buf[rl][(h2 - 4) * 16 + j] = acc16[j];
    }
    __syncthreads();
    if (t < 128) {
        int c = t & 63;
        float s = 0.0f;
        if (t < 64) { for (int r = 0; r < ROWS; ++r) s += buf[r][c]; }
        else        { for (int r = 0; r < ROWS; ++r) { float v = buf[r][c]; s = fmaf(v, v, s); } }
        part3[blockIdx.x * 256 + 128 + t] = s;
    }
}

// ---------------- D: stats3 + final normalize in place ----------------
__global__ __launch_bounds__(256) void bnf_kernel(float* __restrict__ Y3,
                                                  const float* __restrict__ g2,
                                                  const float* __restrict__ be2,
                                                  const float* __restrict__ part3) {
    __shared__ float red[256];
    __shared__ float scs[128], shs[128];
    int t = threadIdx.x;
    {
        float s = 0.0f;
#pragma unroll 8
        for (int g = 0; g < NBLK; ++g) s += part3[(size_t)g * 256 + t];
        red[t] = s;
    }
    __syncthreads();
    if (t < 128) {
        int si = (t < 64) ? t : (t + 64);
        float mean = red[si] * (1.0f / BN_);
        float var = red[si + 64] * (1.0f / BN_) - mean * mean;
        float rstd = rsqrtf(var + EPS_);
        float scl = rstd * g2[t];
        scs[t] = scl;
        shs[t] = be2[t] - mean * scl;
    }
    __syncthreads();
    const int total = BN_ * 128 / 4;
    float4* p = (float4*)Y3;
    for (int i = blockIdx.x * 256 + t; i < total; i += 256 * 256) {
        float4 v = p[i];
        int c0 = (i * 4) & 127;
        v.x = fmaxf(0.0f, fmaf(v.x, scs[c0],     shs[c0]));
        v.y = fmaxf(0.0f, fmaf(v.y, scs[c0 + 1], shs[c0 + 1]));
        v.z = fmaxf(0.0f, fmaf(v.z, scs[c0 + 2], shs[c0 + 2]));
        v.w = fmaxf(0.0f, fmaf(v.w, scs[c0 + 3], shs[c0 + 3]));
        p[i] = v;
    }
}

extern "C" void kernel_launch(void* const* d_in, const int* in_sizes, int n_in,
                              void* d_out, int out_size, void* d_ws, size_t ws_size,
                              hipStream_t stream) {
    const float* coords = (const float*)d_in[0];
    const float* feats  = (const float*)d_in[1];
    const float* W1  = (const float*)d_in[3];
    const float* b1  = (const float*)d_in[4];
    const float* g1  = (const float*)d_in[5];
    const float* be1 = (const float*)d_in[6];
    const float* Wa  = (const float*)d_in[7];
    const float* ba  = (const float*)d_in[8];
    const float* ga  = (const float*)d_in[9];
    const float* bea = (const float*)d_in[10];
    const float* W2  = (const float*)d_in[11];
    const float* b2  = (const float*)d_in[12];
    const float* g2  = (const float*)d_in[13];
    const float* be2 = (const float*)d_in[14];

    float* ws = (float*)d_ws;
    float4* coords4 = (float4*)ws;                         // 131072 f
    int*    idxbuf  = (int*)(ws + 131072);                 // BN_*16 ints
    __half* fh      = (__half*)(ws + 131072 + 524288);     // BN_*64 halves
    float*  y1 = ws + 131072 + 524288 + 1048576;           // BN_*64
    float*  x1 = y1 + (size_t)BN_ * 64;
    float*  y2 = x1 + (size_t)BN_ * 64;
    float*  part1 = y2 + (size_t)BN_ * 64;                 // NBLK*128
    float*  part2 = part1 + NBLK * 128;
    float*  part3 = part2 + NBLK * 128;                    // NBLK*256
    float*  y3 = (float*)d_out;

    pack_coords<<<(BN_ + 255) / 256, 256, 0, stream>>>(coords, coords4);
    feats2h<<<BN_ * 64 / 8 / 256, 256, 0, stream>>>(feats, fh);
    knn_reg<<<B_ * 128, KT_, 0, stream>>>(coords4, idxbuf);

    g1_kernel<<<NBLK, 512, 0, stream>>>(fh, idxbuf, W1, b1, y1, part1);
    m2_kernel<<<NBLK, 512, 0, stream>>>(y1, Wa, ba, g1, be1, part1, x1, y2, part2);
    m3_kernel<<<NBLK, 512, 0, stream>>>(y2, x1, W2, b2, ga, bea, part2, y3, part3);
    bnf_kernel<<<256, 256, 0, stream>>>(y3, g2, be2, part3);
}

// Round 17
// 290.069 us; speedup vs baseline: 1.0026x; 1.0026x over previous
//
#include <hip/hip_runtime.h>
#include <hip/hip_bf16.h>
#include <hip/hip_fp16.h>
#include <math.h>

#define B_ 4
#define N_ 8192
#define K_ 16
#define BN_ (B_ * N_)
#define EPS_ 1e-5f

#define KW_ 8                 // waves per knn block
#define KT_ (KW_ * 64)        // 512 threads
#define MCAND (N_ / KW_)      // 1024 candidates per wave slice
#define DEPTH 16              // deferred-insert buffer depth

#define NBLK 512              // tail grid
#define ROWS 64               // rows per tail block (8 threads/row)

#define KEY_SENTINEL 0x7F800000FFFFFFFFULL   // (+inf distance, max idx)

// ---------------- pack coords (B*N,3) -> float4 ----------------
__global__ __launch_bounds__(256) void pack_coords(const float* __restrict__ coords,
                                                   float4* __restrict__ out) {
    int i = blockIdx.x * 256 + threadIdx.x;
    if (i >= BN_) return;
    out[i] = make_float4(coords[3 * i], coords[3 * i + 1], coords[3 * i + 2], 0.0f);
}

// ---------------- feats fp32 -> fp16 ----------------
__global__ __launch_bounds__(256) void feats2h(const float* __restrict__ in,
                                               __half* __restrict__ outh) {
    int i = blockIdx.x * 256 + threadIdx.x;
    const float4* p = (const float4*)(in + (size_t)i * 8);
    float4 a = p[0], b = p[1];
    __half2 h0; h0.x = __float2half_rn(a.x); h0.y = __float2half_rn(a.y);
    __half2 h1; h1.x = __float2half_rn(a.z); h1.y = __float2half_rn(a.w);
    __half2 h2; h2.x = __float2half_rn(b.x); h2.y = __float2half_rn(b.y);
    __half2 h3; h3.x = __float2half_rn(b.z); h3.y = __float2half_rn(b.w);
    uint4 o;
    o.x = *(unsigned*)&h0; o.y = *(unsigned*)&h1; o.z = *(unsigned*)&h2; o.w = *(unsigned*)&h3;
    ((uint4*)outh)[i] = o;
}

// ---------------- exact 16-NN: two-phase select, REGISTER histogram ----------------
// r15's structure (lane = query, wave w scans contiguous slice with wave-uniform
// s_load broadcast), but phase 1's histogram lives in ONE u64 register: 8 buckets
// x u8 fields, bucket = clamp((exp(d2)-118)>>1, 0, 7), acc += 1<<(bk*8).
// Pure VALU, 1-cycle dep chain, zero LDS (r15's 16.8M bank conflicts + rmw
// serialization eliminated). u8 wrap is conservative-safe: wrap only lowers
// reported counts -> looser T -> still exact. Cross-wave merge: 8 u64s via LDS
// once, summed field-wise after even/odd 8->16-bit spread (max 8*255 < 2^16).
// T = upper d2 edge of bucket B where cumulative count reaches 16 (B=7 -> inf).
// PHASE 2 rescans pushing only d2 < T. Keys (d2<<32)|idx -> deterministic.
__global__ __launch_bounds__(KT_) void knn_reg(const float4* __restrict__ coords4,
                                               int* __restrict__ idxOut) {
    __shared__ unsigned long long bufp[DEPTH][KT_];    // 64 KB
    __shared__ unsigned long long accs[KW_][64];       // 4 KB

    int t = threadIdx.x;
    int lane = t & 63;
    int w = __builtin_amdgcn_readfirstlane(t >> 6);
    int b = blockIdx.x >> 7;
    int g = blockIdx.x & 127;

    const float4* cb = coords4 + (size_t)b * N_;
    int q = g * 64 + lane;
    float4 qc = cb[q];
    float qx = qc.x, qy = qc.y, qz = qc.z;

    const int base = w * MCAND;

    // ---- phase 1: register histogram over own slice
    unsigned long long acc = 0;
    for (int i = 0; i < MCAND; i += 8) {
        float4 c0 = cb[base + i + 0];
        float4 c1 = cb[base + i + 1];
        float4 c2 = cb[base + i + 2];
        float4 c3 = cb[base + i + 3];
        float4 c4 = cb[base + i + 4];
        float4 c5 = cb[base + i + 5];
        float4 c6 = cb[base + i + 6];
        float4 c7 = cb[base + i + 7];
#define H1(cv)                                                         \
        {                                                              \
            float dx = qx - cv.x, dy = qy - cv.y, dz = qz - cv.z;      \
            float d2 = dx * dx;                                        \
            d2 = fmaf(dy, dy, d2);                                     \
            d2 = fmaf(dz, dz, d2);                                     \
            int e = (int)(__float_as_uint(d2) >> 23);                  \
            int bk = (e - 118) >> 1;                                   \
            bk = bk < 0 ? 0 : (bk > 7 ? 7 : bk);                       \
            acc += 1ULL << (bk << 3);                                  \
        }
        H1(c0) H1(c1) H1(c2) H1(c3) H1(c4) H1(c5) H1(c6) H1(c7)
#undef H1
    }
    accs[w][lane] = acc;
    __syncthreads();

    // ---- per-query threshold from cross-wave cumulative histogram
    float T;
    {
        const unsigned long long M8 = 0x00FF00FF00FF00FFULL;
        unsigned long long se = 0, so = 0;   // 16-bit fields: buckets 0,2,4,6 / 1,3,5,7
#pragma unroll
        for (int ww = 0; ww < KW_; ++ww) {
            unsigned long long a = accs[ww][lane];
            se += a & M8;
            so += (a >> 8) & M8;
        }
        int cum = 0;
        int B = 8;
#pragma unroll
        for (int bb = 0; bb < 8; ++bb) {
            unsigned long long s = (bb & 1) ? so : se;
            int c = (int)((s >> ((bb >> 1) << 4)) & 0xFFFF);
            cum += c;
            if (cum >= K_ && B == 8) B = bb;
        }
        // bucket bb holds exponents {118+2bb, 118+2bb+1}; upper edge = 2^(118+2bb+2-127)
        T = (B >= 7) ? 3.4e38f : __uint_as_float((unsigned)(118 + 2 * B + 2) << 23);
    }

    // ---- phase 2: rescan, push only d2 < limf (starts at T)
    unsigned long long key[K_];
#pragma unroll
    for (int j = 0; j < K_; j++) key[j] = KEY_SENTINEL;

    int cnt = 0;
    float limf = T;

    auto flush = [&]() {
        for (int j = 0; j < cnt; ++j) {
            unsigned long long e = bufp[j][t];
            if (e < key[K_ - 1]) {
#pragma unroll
                for (int jj = K_ - 1; jj > 0; --jj) {
                    bool up = e < key[jj - 1];
                    unsigned long long lo = (e < key[jj]) ? e : key[jj];
                    key[jj] = up ? key[jj - 1] : lo;
                }
                if (e < key[0]) key[0] = e;
            }
        }
        cnt = 0;
        float own = __uint_as_float((unsigned)(key[K_ - 1] >> 32));
        limf = fminf(own, T);
    };

    for (int i = 0; i < MCAND; i += 8) {
        float4 c0 = cb[base + i + 0];
        float4 c1 = cb[base + i + 1];
        float4 c2 = cb[base + i + 2];
        float4 c3 = cb[base + i + 3];
        float4 c4 = cb[base + i + 4];
        float4 c5 = cb[base + i + 5];
        float4 c6 = cb[base + i + 6];
        float4 c7 = cb[base + i + 7];
#define P2(cv, mm)                                                     \
        {                                                              \
            float dx = qx - cv.x, dy = qy - cv.y, dz = qz - cv.z;      \
            float d2 = dx * dx;                                        \
            d2 = fmaf(dy, dy, d2);                                     \
            d2 = fmaf(dz, dz, d2);                                     \
            if (d2 < limf) {                                           \
                bufp[cnt][t] = ((unsigned long long)__float_as_uint(d2) << 32) | \
                               (unsigned)(mm);                         \
                cnt++;                                                 \
            }                                                          \
        }
        P2(c0, base + i + 0) P2(c1, base + i + 1) P2(c2, base + i + 2) P2(c3, base + i + 3)
        P2(c4, base + i + 4) P2(c5, base + i + 5) P2(c6, base + i + 6) P2(c7, base + i + 7)
#undef P2
        // each lane pushed at most 8 since last check; DEPTH-7 guard => no overflow
        if (__any(cnt >= DEPTH - 7)) flush();
    }
    flush();

    // ---- publish sorted lists; tree-merge 8 -> 1 per query
#pragma unroll
    for (int j = 0; j < K_; j++) bufp[j][t] = key[j];

    int* op = idxOut + ((size_t)b * N_ + q) * K_;
    for (int step = 1; step < KW_; step <<= 1) {
        bool active = (w & (2 * step - 1)) == 0;
        unsigned long long md[K_];
        __syncthreads();
        if (active) {
            int pa = t, pb = t + step * 64;
            int ia = 0, ib = 0;
#pragma unroll
            for (int r2 = 0; r2 < K_; ++r2) {
                unsigned long long ea = bufp[ia][pa];
                unsigned long long eb = bufp[ib][pb];
                bool sel = ea <= eb;
                md[r2] = sel ? ea : eb;
                ia += sel ? 1 : 0;
                ib += sel ? 0 : 1;
            }
        }
        __syncthreads();
        if (active) {
            if (step == KW_ / 2) {
#pragma unroll
                for (int r2 = 0; r2 < K_; ++r2) op[r2] = (int)(md[r2] & 0xFFFFFFFFu);
            } else {
#pragma unroll
                for (int r2 = 0; r2 < K_; ++r2) bufp[r2][t] = md[r2];
            }
        }
    }
}

// ---------------- A: fp16 gather (XCD-swizzled) + mean + mm1 + part1 ----------------
__global__ __launch_bounds__(512) void g1_kernel(const __half* __restrict__ fh,
                                                 const int* __restrict__ idx,
                                                 const float* __restrict__ W1,
                                                 const float* __restrict__ b1,
                                                 float* __restrict__ Y1,
                                                 float* __restrict__ part1) {
    __shared__ float buf[ROWS][65];
    int t = threadIdx.x;
    int rl = t & 63;
    int h2 = __builtin_amdgcn_readfirstlane(t >> 6);
    int vbid = ((blockIdx.x & 7) << 6) + (blockIdx.x >> 3);   // XCD-contiguous
    int row = vbid * ROWS + rl;
    int bb = row >> 13;

    const __half* fb = fh + ((size_t)bb << 13) * 64;
    const int* ip = idx + (size_t)row * K_;

    float xh[8];
#pragma unroll
    for (int j = 0; j < 8; j++) xh[j] = 0.0f;
#pragma unroll
    for (int j = 0; j < K_; j++) {
        uint4 a = *(const uint4*)(fb + (((size_t)ip[j]) << 6) + h2 * 8);
        __half2* hp = (__half2*)&a;
#pragma unroll
        for (int p = 0; p < 4; p++) {
            float2 f = __half22float2(hp[p]);
            xh[2 * p] += f.x;
            xh[2 * p + 1] += f.y;
        }
    }
#pragma unroll
    for (int j = 0; j < 8; j++) buf[rl][h2 * 8 + j] = xh[j] * (1.0f / 16.0f);
    __syncthreads();

    float acc[8];
#pragma unroll
    for (int j = 0; j < 8; j++) acc[j] = b1[h2 * 8 + j];
#pragma unroll 1
    for (int c0 = 0; c0 < 64; c0 += 16) {
        float xr[16];
#pragma unroll
        for (int j = 0; j < 16; j++) xr[j] = buf[rl][c0 + j];
#pragma unroll
        for (int cc = 0; cc < 16; cc++) {
            float xv = xr[cc];
            const float* wr = W1 + (c0 + cc) * 64 + h2 * 8;
#pragma unroll
            for (int j = 0; j < 8; j++) acc[j] = fmaf(xv, wr[j], acc[j]);
        }
    }
    float2* yp = (float2*)(Y1 + (size_t)row * 64 + h2 * 8);
#pragma unroll
    for (int f = 0; f < 4; f++) yp[f] = make_float2(acc[2 * f], acc[2 * f + 1]);
    __syncthreads();
#pragma unroll
    for (int j = 0; j < 8; j++) buf[rl][h2 * 8 + j] = acc[j];
    __syncthreads();
    if (t < 128) {
        int c = t & 63;
        float s = 0.0f;
        if (t < 64) { for (int r = 0; r < ROWS; ++r) s += buf[r][c]; }
        else        { for (int r = 0; r < ROWS; ++r) { float v = buf[r][c]; s = fmaf(v, v, s); } }
        part1[blockIdx.x * 128 + t] = s;
    }
}

// ---------------- shared: reduce [NBLK][128] partials -> scs/shs (64 ch) ----------------
__device__ __forceinline__ void reduce_stats64(const float* __restrict__ part,
                                               const float* __restrict__ gma,
                                               const float* __restrict__ bta,
                                               float* red4, float* scs, float* shs) {
    int t = threadIdx.x;
    {
        int c = t & 127;
        int q = t >> 7;
        float s = 0.0f;
#pragma unroll 8
        for (int g = q * 128; g < q * 128 + 128; ++g) s += part[(size_t)g * 128 + c];
        red4[t] = s;
    }
    __syncthreads();
    if (t < 128) red4[t] = red4[t] + red4[t + 128] + red4[t + 256] + red4[t + 384];
    __syncthreads();
    if (t < 64) {
        float mean = red4[t] * (1.0f / BN_);
        float var = red4[t + 64] * (1.0f / BN_) - mean * mean;
        float rstd = rsqrtf(var + EPS_);
        float scl = rstd * gma[t];
        scs[t] = scl;
        shs[t] = bta[t] - mean * scl;
    }
    __syncthreads();
}

// ---------------- B: stats1 + bn1/relu -> x1, mm2 -> y2 + part2 ----------------
__global__ __launch_bounds__(512) void m2_kernel(const float* __restrict__ Y1,
                                                 const float* __restrict__ Wa,
                                                 const float* __restrict__ ba,
                                                 const float* __restrict__ g1,
                                                 const float* __restrict__ be1,
                                                 const float* __restrict__ part1,
                                                 float* __restrict__ X1,
                                                 float* __restrict__ Y2,
                                                 float* __restrict__ part2) {
    __shared__ float buf[ROWS][65];
    __shared__ float red4[512];
    __shared__ float scs[64], shs[64];
    int t = threadIdx.x;
    int rl = t & 63;
    int h2 = __builtin_amdgcn_readfirstlane(t >> 6);
    int row = blockIdx.x * ROWS + rl;

    reduce_stats64(part1, g1, be1, red4, scs, shs);

    const float2* y1p = (const float2*)(Y1 + (size_t)row * 64 + h2 * 8);
    float2* x1p = (float2*)(X1 + (size_t)row * 64 + h2 * 8);
#pragma unroll
    for (int f = 0; f < 4; f++) {
        float2 v = y1p[f];
        int c0 = h2 * 8 + 2 * f;
        float a = fmaxf(0.0f, fmaf(v.x, scs[c0], shs[c0]));
        float b = fmaxf(0.0f, fmaf(v.y, scs[c0 + 1], shs[c0 + 1]));
        x1p[f] = make_float2(a, b);
        buf[rl][c0] = a;
        buf[rl][c0 + 1] = b;
    }
    __syncthreads();

    float acc[8];
#pragma unroll
    for (int j = 0; j < 8; j++) acc[j] = ba[h2 * 8 + j];
#pragma unroll 1
    for (int c0 = 0; c0 < 64; c0 += 16) {
        float xr[16];
#pragma unroll
        for (int j = 0; j < 16; j++) xr[j] = buf[rl][c0 + j];
#pragma unroll
        for (int cc = 0; cc < 16; cc++) {
            float xv = xr[cc];
            const float* wr = Wa + (c0 + cc) * 64 + h2 * 8;
#pragma unroll
            for (int j = 0; j < 8; j++) acc[j] = fmaf(xv, wr[j], acc[j]);
        }
    }
    float2* y2p = (float2*)(Y2 + (size_t)row * 64 + h2 * 8);
#pragma unroll
    for (int f = 0; f < 4; f++) y2p[f] = make_float2(acc[2 * f], acc[2 * f + 1]);
    __syncthreads();
#pragma unroll
    for (int j = 0; j < 8; j++) buf[rl][h2 * 8 + j] = acc[j];
    __syncthreads();
    if (t < 128) {
        int c = t & 63;
        float s = 0.0f;
        if (t < 64) { for (int r = 0; r < ROWS; ++r) s += buf[r][c]; }
        else        { for (int r = 0; r < ROWS; ++r) { float v = buf[r][c]; s = fmaf(v, v, s); } }
        part2[blockIdx.x * 128 + t] = s;
    }
}

// ---------------- C: stats2 + attn + fused, mm3 -> y3(unnorm) + part3 ----------------
__global__ __launch_bounds__(512) void m3_kernel(const float* __restrict__ Y2,
                                                 const float* __restrict__ X1,
                                                 const float* __restrict__ W2,
                                                 const float* __restrict__ b2,
                                                 const float* __restrict__ ga,
                                                 const float* __restrict__ bea,
                                                 const float* __restrict__ part2,
                                                 float* __restrict__ Y3,
                                                 float* __restrict__ part3) {
    __shared__ float buf[ROWS][65];
    __shared__ float red4[512];
    __shared__ float scs[64], shs[64];
    int t = threadIdx.x;
    int rl = t & 63;
    int h2 = __builtin_amdgcn_readfirstlane(t >> 6);
    int row = blockIdx.x * ROWS + rl;

    reduce_stats64(part2, ga, bea, red4, scs, shs);

    const float2* y2p = (const float2*)(Y2 + (size_t)row * 64 + h2 * 8);
    const float2* x1p = (const float2*)(X1 + (size_t)row * 64 + h2 * 8);
#pragma unroll
    for (int f = 0; f < 4; f++) {
        float2 v = y2p[f];
        float2 u = x1p[f];
        int c0 = h2 * 8 + 2 * f;
        float t0 = fmaxf(0.0f, fmaf(v.x, scs[c0], shs[c0]));
        float t1 = fmaxf(0.0f, fmaf(v.y, scs[c0 + 1], shs[c0 + 1]));
        float a0 = 1.0f / (1.0f + __expf(-t0));
        float a1 = 1.0f / (1.0f + __expf(-t1));
        buf[rl][c0] = u.x * (1.0f + a0);
        buf[rl][c0 + 1] = u.y * (1.0f + a1);
    }
    __syncthreads();

    float acc16[16];
#pragma unroll
    for (int j = 0; j < 16; j++) acc16[j] = b2[h2 * 16 + j];
#pragma unroll 1
    for (int c0 = 0; c0 < 64; c0 += 16) {
        float xr[16];
#pragma unroll
        for (int j = 0; j < 16; j++) xr[j] = buf[rl][c0 + j];
#pragma unroll
        for (int cc = 0; cc < 16; cc++) {
            float xv = xr[cc];
            const float* wr = W2 + (c0 + cc) * 128 + h2 * 16;
#pragma unroll
            for (int j = 0; j < 16; j++) acc16[j] = fmaf(xv, wr[j], acc16[j]);
        }
    }
    float4* yp = (float4*)(Y3 + (size_t)row * 128 + h2 * 16);
#pragma unroll
    for (int f = 0; f < 4; f++)
        yp[f] = make_float4(acc16[4 * f], acc16[4 * f + 1], acc16[4 * f + 2], acc16[4 * f + 3]);

    __syncthreads();
    if (h2 < 4) {
#pragma unroll
        for (int j = 0; j < 16; j++) buf[rl][h2 * 16 + j] = acc16[j];
    }
    __syncthreads();
    if (t < 128) {
        int c = t & 63;
        float s = 0.0f;
        if (t < 64) { for (int r = 0; r < ROWS; ++r) s += buf[r][c]; }
        else        { for (int r = 0; r < ROWS; ++r) { float v = buf[r][c]; s = fmaf(v, v, s); } }
        part3[blockIdx.x * 256 + t] = s;
    }
    __syncthreads();
    if (h2 >= 4) {
#pragma unroll
        for (int j = 0; j < 16; j++) buf[rl][(h2 - 4) * 16 + j] = acc16[j];
    }
    __syncthreads();
    if (t < 128) {
        int c = t & 63;
        float s = 0.0f;
        if (t < 64) { for (int r = 0; r < ROWS; ++r) s += buf[r][c]; }
        else        { for (int r = 0; r < ROWS; ++r) { float v = buf[r][c]; s = fmaf(v, v, s); } }
        part3[blockIdx.x * 256 + 128 + t] = s;
    }
}

// ---------------- D: stats3 + final normalize in place ----------------
__global__ __launch_bounds__(256) void bnf_kernel(float* __restrict__ Y3,
                                                  const float* __restrict__ g2,
                                                  const float* __restrict__ be2,
                                                  const float* __restrict__ part3) {
    __shared__ float red[256];
    __shared__ float scs[128], shs[128];
    int t = threadIdx.x;
    {
        float s = 0.0f;
#pragma unroll 8
        for (int g = 0; g < NBLK; ++g) s += part3[(size_t)g * 256 + t];
        red[t] = s;
    }
    __syncthreads();
    if (t < 128) {
        int si = (t < 64) ? t : (t + 64);
        float mean = red[si] * (1.0f / BN_);
        float var = red[si + 64] * (1.0f / BN_) - mean * mean;
        float rstd = rsqrtf(var + EPS_);
        float scl = rstd * g2[t];
        scs[t] = scl;
        shs[t] = be2[t] - mean * scl;
    }
    __syncthreads();
    const int total = BN_ * 128 / 4;
    float4* p = (float4*)Y3;
    for (int i = blockIdx.x * 256 + t; i < total; i += 256 * 256) {
        float4 v = p[i];
        int c0 = (i * 4) & 127;
        v.x = fmaxf(0.0f, fmaf(v.x, scs[c0],     shs[c0]));
        v.y = fmaxf(0.0f, fmaf(v.y, scs[c0 + 1], shs[c0 + 1]));
        v.z = fmaxf(0.0f, fmaf(v.z, scs[c0 + 2], shs[c0 + 2]));
        v.w = fmaxf(0.0f, fmaf(v.w, scs[c0 + 3], shs[c0 + 3]));
        p[i] = v;
    }
}

extern "C" void kernel_launch(void* const* d_in, const int* in_sizes, int n_in,
                              void* d_out, int out_size, void* d_ws, size_t ws_size,
                              hipStream_t stream) {
    const float* coords = (const float*)d_in[0];
    const float* feats  = (const float*)d_in[1];
    const float* W1  = (const float*)d_in[3];
    const float* b1  = (const float*)d_in[4];
    const float* g1  = (const float*)d_in[5];
    const float* be1 = (const float*)d_in[6];
    const float* Wa  = (const float*)d_in[7];
    const float* ba  = (const float*)d_in[8];
    const float* ga  = (const float*)d_in[9];
    const float* bea = (const float*)d_in[10];
    const float* W2  = (const float*)d_in[11];
    const float* b2  = (const float*)d_in[12];
    const float* g2  = (const float*)d_in[13];
    const float* be2 = (const float*)d_in[14];

    float* ws = (float*)d_ws;
    float4* coords4 = (float4*)ws;                         // 131072 f
    int*    idxbuf  = (int*)(ws + 131072);                 // BN_*16 ints
    __half* fh      = (__half*)(ws + 131072 + 524288);     // BN_*64 halves
    float*  y1 = ws + 131072 + 524288 + 1048576;           // BN_*64
    float*  x1 = y1 + (size_t)BN_ * 64;
    float*  y2 = x1 + (size_t)BN_ * 64;
    float*  part1 = y2 + (size_t)BN_ * 64;                 // NBLK*128
    float*  part2 = part1 + NBLK * 128;
    float*  part3 = part2 + NBLK * 128;                    // NBLK*256
    float*  y3 = (float*)d_out;

    pack_coords<<<(BN_ + 255) / 256, 256, 0, stream>>>(coords, coords4);
    feats2h<<<BN_ * 64 / 8 / 256, 256, 0, stream>>>(feats, fh);
    knn_reg<<<B_ * 128, KT_, 0, stream>>>(coords4, idxbuf);

    g1_kernel<<<NBLK, 512, 0, stream>>>(fh, idxbuf, W1, b1, y1, part1);
    m2_kernel<<<NBLK, 512, 0, stream>>>(y1, Wa, ba, g1, be1, part1, x1, y2, part2);
    m3_kernel<<<NBLK, 512, 0, stream>>>(y2, x1, W2, b2, ga, bea, part2, y3, part3);
    bnf_kernel<<<256, 256, 0, stream>>>(y3, g2, be2, part3);
}

// Round 18
// 268.110 us; speedup vs baseline: 1.0847x; 1.0819x over previous
//
#include <hip/hip_runtime.h>
#include <hip/hip_bf16.h>
#include <hip/hip_fp16.h>
#include <math.h>

#define B_ 4
#define N_ 8192
#define K_ 16
#define BN_ (B_ * N_)
#define EPS_ 1e-5f

#define KW_ 8                 // waves per knn block
#define KT_ (KW_ * 64)        // 512 threads
#define MCAND (N_ / KW_)      // 1024 candidates per wave slice
#define SAMP 256              // phase-A sample per wave (contiguous prefix)
#define DEPTH 16              // deferred-insert buffer depth

#define NBLK 512              // tail grid
#define ROWS 64               // rows per tail block (8 threads/row)

#define KEY_SENTINEL 0x7F800000FFFFFFFFULL   // (+inf distance, max idx)

// ---------------- pack coords (B*N,3) -> float4 ----------------
__global__ __launch_bounds__(256) void pack_coords(const float* __restrict__ coords,
                                                   float4* __restrict__ out) {
    int i = blockIdx.x * 256 + threadIdx.x;
    if (i >= BN_) return;
    out[i] = make_float4(coords[3 * i], coords[3 * i + 1], coords[3 * i + 2], 0.0f);
}

// ---------------- feats fp32 -> fp16 ----------------
__global__ __launch_bounds__(256) void feats2h(const float* __restrict__ in,
                                               __half* __restrict__ outh) {
    int i = blockIdx.x * 256 + threadIdx.x;
    const float4* p = (const float4*)(in + (size_t)i * 8);
    float4 a = p[0], b = p[1];
    __half2 h0; h0.x = __float2half_rn(a.x); h0.y = __float2half_rn(a.y);
    __half2 h1; h1.x = __float2half_rn(a.z); h1.y = __float2half_rn(a.w);
    __half2 h2; h2.x = __float2half_rn(b.x); h2.y = __float2half_rn(b.y);
    __half2 h3; h3.x = __float2half_rn(b.z); h3.y = __float2half_rn(b.w);
    uint4 o;
    o.x = *(unsigned*)&h0; o.y = *(unsigned*)&h1; o.z = *(unsigned*)&h2; o.w = *(unsigned*)&h3;
    ((uint4*)outh)[i] = o;
}

// ---------------- exact 16-NN: subsampled histogram + one cheap full pass ----------------
// Lane = query, wave w owns contiguous slice [w*1024,(w+1)*1024) (dense
// wave-uniform s_load stream). PHASE A: register u64 histogram (8 x u8 buckets,
// bucket = clamp((exp(d2)-118)>>1,0,7)) over only the FIRST 256 candidates of
// the slice (a uniform random sample; input order is random). Cross-wave merge
// -> T = upper d2 edge of bucket where the 2048-sample cumulative count reaches
// 16. T >= sample d16 >= true d16: exact upper bound. u8 wrap & coarse buckets
// only loosen T -> still exact. PHASE B: full-slice scan pushing d2 <= limf
// (init T, shrinks to own 16th) into per-lane LDS buffers; 16-deep u64 insertion
// only on (rare) flushes. Keys (d2_bits<<32)|idx -> unique total order ->
// deterministic output.
__global__ __launch_bounds__(KT_) void knn_2ph(const float4* __restrict__ coords4,
                                               int* __restrict__ idxOut) {
    __shared__ unsigned long long bufp[DEPTH][KT_];    // 64 KB
    __shared__ unsigned long long accs[KW_][64];       // 4 KB

    int t = threadIdx.x;
    int lane = t & 63;
    int w = __builtin_amdgcn_readfirstlane(t >> 6);
    int b = blockIdx.x >> 7;
    int g = blockIdx.x & 127;

    const float4* cb = coords4 + (size_t)b * N_;
    int q = g * 64 + lane;
    float4 qc = cb[q];
    float qx = qc.x, qy = qc.y, qz = qc.z;

    const int base = w * MCAND;

    // ---- phase A: register histogram over first SAMP candidates of own slice
    unsigned long long acc = 0;
    for (int i = 0; i < SAMP; i += 8) {
        float4 c0 = cb[base + i + 0];
        float4 c1 = cb[base + i + 1];
        float4 c2 = cb[base + i + 2];
        float4 c3 = cb[base + i + 3];
        float4 c4 = cb[base + i + 4];
        float4 c5 = cb[base + i + 5];
        float4 c6 = cb[base + i + 6];
        float4 c7 = cb[base + i + 7];
#define H1(cv)                                                         \
        {                                                              \
            float dx = qx - cv.x, dy = qy - cv.y, dz = qz - cv.z;      \
            float d2 = dx * dx;                                        \
            d2 = fmaf(dy, dy, d2);                                     \
            d2 = fmaf(dz, dz, d2);                                     \
            int e = (int)(__float_as_uint(d2) >> 23);                  \
            int bk = (e - 118) >> 1;                                   \
            bk = bk < 0 ? 0 : (bk > 7 ? 7 : bk);                       \
            acc += 1ULL << (bk << 3);                                  \
        }
        H1(c0) H1(c1) H1(c2) H1(c3) H1(c4) H1(c5) H1(c6) H1(c7)
#undef H1
    }
    accs[w][lane] = acc;
    __syncthreads();

    // ---- per-query threshold from cross-wave cumulative sample histogram
    float T;
    {
        const unsigned long long M8 = 0x00FF00FF00FF00FFULL;
        unsigned long long se = 0, so = 0;   // 16-bit fields: buckets 0,2,4,6 / 1,3,5,7
#pragma unroll
        for (int ww = 0; ww < KW_; ++ww) {
            unsigned long long a = accs[ww][lane];
            se += a & M8;
            so += (a >> 8) & M8;
        }
        int cum = 0;
        int B = 8;
#pragma unroll
        for (int bb = 0; bb < 8; ++bb) {
            unsigned long long s = (bb & 1) ? so : se;
            int c = (int)((s >> ((bb >> 1) << 4)) & 0xFFFF);
            cum += c;
            if (cum >= K_ && B == 8) B = bb;
        }
        // bucket bb holds exponents {118+2bb, 118+2bb+1}; upper edge = 2^(118+2bb+2-127)
        T = (B >= 7) ? 3.4e38f : __uint_as_float((unsigned)(118 + 2 * B + 2) << 23);
    }

    // ---- phase B: full-slice scan, push only d2 <= limf (starts at T)
    unsigned long long key[K_];
#pragma unroll
    for (int j = 0; j < K_; j++) key[j] = KEY_SENTINEL;

    int cnt = 0;
    float limf = T;

    auto flush = [&]() {
        for (int j = 0; j < cnt; ++j) {
            unsigned long long e = bufp[j][t];
            if (e < key[K_ - 1]) {
#pragma unroll
                for (int jj = K_ - 1; jj > 0; --jj) {
                    bool up = e < key[jj - 1];
                    unsigned long long lo = (e < key[jj]) ? e : key[jj];
                    key[jj] = up ? key[jj - 1] : lo;
                }
                if (e < key[0]) key[0] = e;
            }
        }
        cnt = 0;
        float own = __uint_as_float((unsigned)(key[K_ - 1] >> 32));
        limf = fminf(own, T);
    };

    for (int i = 0; i < MCAND; i += 8) {
        float4 c0 = cb[base + i + 0];
        float4 c1 = cb[base + i + 1];
        float4 c2 = cb[base + i + 2];
        float4 c3 = cb[base + i + 3];
        float4 c4 = cb[base + i + 4];
        float4 c5 = cb[base + i + 5];
        float4 c6 = cb[base + i + 6];
        float4 c7 = cb[base + i + 7];
#define P2(cv, mm)                                                     \
        {                                                              \
            float dx = qx - cv.x, dy = qy - cv.y, dz = qz - cv.z;      \
            float d2 = dx * dx;                                        \
            d2 = fmaf(dy, dy, d2);                                     \
            d2 = fmaf(dz, dz, d2);                                     \
            if (d2 <= limf) {                                          \
                bufp[cnt][t] = ((unsigned long long)__float_as_uint(d2) << 32) | \
                               (unsigned)(mm);                         \
                cnt++;                                                 \
            }                                                          \
        }
        P2(c0, base + i + 0) P2(c1, base + i + 1) P2(c2, base + i + 2) P2(c3, base + i + 3)
        P2(c4, base + i + 4) P2(c5, base + i + 5) P2(c6, base + i + 6) P2(c7, base + i + 7)
#undef P2
        // each lane pushed at most 8 since last check; DEPTH-7 guard => no overflow
        if (__any(cnt >= DEPTH - 7)) flush();
    }
    flush();

    // ---- publish sorted lists; tree-merge 8 -> 1 per query
#pragma unroll
    for (int j = 0; j < K_; j++) bufp[j][t] = key[j];

    int* op = idxOut + ((size_t)b * N_ + q) * K_;
    for (int step = 1; step < KW_; step <<= 1) {
        bool active = (w & (2 * step - 1)) == 0;
        unsigned long long md[K_];
        __syncthreads();
        if (active) {
            int pa = t, pb = t + step * 64;
            int ia = 0, ib = 0;
#pragma unroll
            for (int r2 = 0; r2 < K_; ++r2) {
                unsigned long long ea = bufp[ia][pa];
                unsigned long long eb = bufp[ib][pb];
                bool sel = ea <= eb;
                md[r2] = sel ? ea : eb;
                ia += sel ? 1 : 0;
                ib += sel ? 0 : 1;
            }
        }
        __syncthreads();
        if (active) {
            if (step == KW_ / 2) {
#pragma unroll
                for (int r2 = 0; r2 < K_; ++r2) op[r2] = (int)(md[r2] & 0xFFFFFFFFu);
            } else {
#pragma unroll
                for (int r2 = 0; r2 < K_; ++r2) bufp[r2][t] = md[r2];
            }
        }
    }
}

// ---------------- A: fp16 gather (XCD-swizzled) + mean + mm1 + part1 ----------------
__global__ __launch_bounds__(512) void g1_kernel(const __half* __restrict__ fh,
                                                 const int* __restrict__ idx,
                                                 const float* __restrict__ W1,
                                                 const float* __restrict__ b1,
                                                 float* __restrict__ Y1,
                                                 float* __restrict__ part1) {
    __shared__ float buf[ROWS][65];
    int t = threadIdx.x;
    int rl = t & 63;
    int h2 = __builtin_amdgcn_readfirstlane(t >> 6);
    int vbid = ((blockIdx.x & 7) << 6) + (blockIdx.x >> 3);   // XCD-contiguous
    int row = vbid * ROWS + rl;
    int bb = row >> 13;

    const __half* fb = fh + ((size_t)bb << 13) * 64;
    const int* ip = idx + (size_t)row * K_;

    float xh[8];
#pragma unroll
    for (int j = 0; j < 8; j++) xh[j] = 0.0f;
#pragma unroll
    for (int j = 0; j < K_; j++) {
        uint4 a = *(const uint4*)(fb + (((size_t)ip[j]) << 6) + h2 * 8);
        __half2* hp = (__half2*)&a;
#pragma unroll
        for (int p = 0; p < 4; p++) {
            float2 f = __half22float2(hp[p]);
            xh[2 * p] += f.x;
            xh[2 * p + 1] += f.y;
        }
    }
#pragma unroll
    for (int j = 0; j < 8; j++) buf[rl][h2 * 8 + j] = xh[j] * (1.0f / 16.0f);
    __syncthreads();

    float acc[8];
#pragma unroll
    for (int j = 0; j < 8; j++) acc[j] = b1[h2 * 8 + j];
#pragma unroll 1
    for (int c0 = 0; c0 < 64; c0 += 16) {
        float xr[16];
#pragma unroll
        for (int j = 0; j < 16; j++) xr[j] = buf[rl][c0 + j];
#pragma unroll
        for (int cc = 0; cc < 16; cc++) {
            float xv = xr[cc];
            const float* wr = W1 + (c0 + cc) * 64 + h2 * 8;
#pragma unroll
            for (int j = 0; j < 8; j++) acc[j] = fmaf(xv, wr[j], acc[j]);
        }
    }
    float2* yp = (float2*)(Y1 + (size_t)row * 64 + h2 * 8);
#pragma unroll
    for (int f = 0; f < 4; f++) yp[f] = make_float2(acc[2 * f], acc[2 * f + 1]);
    __syncthreads();
#pragma unroll
    for (int j = 0; j < 8; j++) buf[rl][h2 * 8 + j] = acc[j];
    __syncthreads();
    if (t < 128) {
        int c = t & 63;
        float s = 0.0f;
        if (t < 64) { for (int r = 0; r < ROWS; ++r) s += buf[r][c]; }
        else        { for (int r = 0; r < ROWS; ++r) { float v = buf[r][c]; s = fmaf(v, v, s); } }
        part1[blockIdx.x * 128 + t] = s;
    }
}

// ---------------- shared: reduce [NBLK][128] partials -> scs/shs (64 ch) ----------------
__device__ __forceinline__ void reduce_stats64(const float* __restrict__ part,
                                               const float* __restrict__ gma,
                                               const float* __restrict__ bta,
                                               float* red4, float* scs, float* shs) {
    int t = threadIdx.x;
    {
        int c = t & 127;
        int q = t >> 7;
        float s = 0.0f;
#pragma unroll 8
        for (int g = q * 128; g < q * 128 + 128; ++g) s += part[(size_t)g * 128 + c];
        red4[t] = s;
    }
    __syncthreads();
    if (t < 128) red4[t] = red4[t] + red4[t + 128] + red4[t + 256] + red4[t + 384];
    __syncthreads();
    if (t < 64) {
        float mean = red4[t] * (1.0f / BN_);
        float var = red4[t + 64] * (1.0f / BN_) - mean * mean;
        float rstd = rsqrtf(var + EPS_);
        float scl = rstd * gma[t];
        scs[t] = scl;
        shs[t] = bta[t] - mean * scl;
    }
    __syncthreads();
}

// ---------------- B: stats1 + bn1/relu -> x1, mm2 -> y2 + part2 ----------------
__global__ __launch_bounds__(512) void m2_kernel(const float* __restrict__ Y1,
                                                 const float* __restrict__ Wa,
                                                 const float* __restrict__ ba,
                                                 const float* __restrict__ g1,
                                                 const float* __restrict__ be1,
                                                 const float* __restrict__ part1,
                                                 float* __restrict__ X1,
                                                 float* __restrict__ Y2,
                                                 float* __restrict__ part2) {
    __shared__ float buf[ROWS][65];
    __shared__ float red4[512];
    __shared__ float scs[64], shs[64];
    int t = threadIdx.x;
    int rl = t & 63;
    int h2 = __builtin_amdgcn_readfirstlane(t >> 6);
    int row = blockIdx.x * ROWS + rl;

    reduce_stats64(part1, g1, be1, red4, scs, shs);

    const float2* y1p = (const float2*)(Y1 + (size_t)row * 64 + h2 * 8);
    float2* x1p = (float2*)(X1 + (size_t)row * 64 + h2 * 8);
#pragma unroll
    for (int f = 0; f < 4; f++) {
        float2 v = y1p[f];
        int c0 = h2 * 8 + 2 * f;
        float a = fmaxf(0.0f, fmaf(v.x, scs[c0], shs[c0]));
        float b = fmaxf(0.0f, fmaf(v.y, scs[c0 + 1], shs[c0 + 1]));
        x1p[f] = make_float2(a, b);
        buf[rl][c0] = a;
        buf[rl][c0 + 1] = b;
    }
    __syncthreads();

    float acc[8];
#pragma unroll
    for (int j = 0; j < 8; j++) acc[j] = ba[h2 * 8 + j];
#pragma unroll 1
    for (int c0 = 0; c0 < 64; c0 += 16) {
        float xr[16];
#pragma unroll
        for (int j = 0; j < 16; j++) xr[j] = buf[rl][c0 + j];
#pragma unroll
        for (int cc = 0; cc < 16; cc++) {
            float xv = xr[cc];
            const float* wr = Wa + (c0 + cc) * 64 + h2 * 8;
#pragma unroll
            for (int j = 0; j < 8; j++) acc[j] = fmaf(xv, wr[j], acc[j]);
        }
    }
    float2* y2p = (float2*)(Y2 + (size_t)row * 64 + h2 * 8);
#pragma unroll
    for (int f = 0; f < 4; f++) y2p[f] = make_float2(acc[2 * f], acc[2 * f + 1]);
    __syncthreads();
#pragma unroll
    for (int j = 0; j < 8; j++) buf[rl][h2 * 8 + j] = acc[j];
    __syncthreads();
    if (t < 128) {
        int c = t & 63;
        float s = 0.0f;
        if (t < 64) { for (int r = 0; r < ROWS; ++r) s += buf[r][c]; }
        else        { for (int r = 0; r < ROWS; ++r) { float v = buf[r][c]; s = fmaf(v, v, s); } }
        part2[blockIdx.x * 128 + t] = s;
    }
}

// ---------------- C: stats2 + attn + fused, mm3 -> y3(unnorm) + part3 ----------------
__global__ __launch_bounds__(512) void m3_kernel(const float* __restrict__ Y2,
                                                 const float* __restrict__ X1,
                                                 const float* __restrict__ W2,
                                                 const float* __restrict__ b2,
                                                 const float* __restrict__ ga,
                                                 const float* __restrict__ bea,
                                                 const float* __restrict__ part2,
                                                 float* __restrict__ Y3,
                                                 float* __restrict__ part3) {
    __shared__ float buf[ROWS][65];
    __shared__ float red4[512];
    __shared__ float scs[64], shs[64];
    int t = threadIdx.x;
    int rl = t & 63;
    int h2 = __builtin_amdgcn_readfirstlane(t >> 6);
    int row = blockIdx.x * ROWS + rl;

    reduce_stats64(part2, ga, bea, red4, scs, shs);

    const float2* y2p = (const float2*)(Y2 + (size_t)row * 64 + h2 * 8);
    const float2* x1p = (const float2*)(X1 + (size_t)row * 64 + h2 * 8);
#pragma unroll
    for (int f = 0; f < 4; f++) {
        float2 v = y2p[f];
        float2 u = x1p[f];
        int c0 = h2 * 8 + 2 * f;
        float t0 = fmaxf(0.0f, fmaf(v.x, scs[c0], shs[c0]));
        float t1 = fmaxf(0.0f, fmaf(v.y, scs[c0 + 1], shs[c0 + 1]));
        float a0 = 1.0f / (1.0f + __expf(-t0));
        float a1 = 1.0f / (1.0f + __expf(-t1));
        buf[rl][c0] = u.x * (1.0f + a0);
        buf[rl][c0 + 1] = u.y * (1.0f + a1);
    }
    __syncthreads();

    float acc16[16];
#pragma unroll
    for (int j = 0; j < 16; j++) acc16[j] = b2[h2 * 16 + j];
#pragma unroll 1
    for (int c0 = 0; c0 < 64; c0 += 16) {
        float xr[16];
#pragma unroll
        for (int j = 0; j < 16; j++) xr[j] = buf[rl][c0 + j];
#pragma unroll
        for (int cc = 0; cc < 16; cc++) {
            float xv = xr[cc];
            const float* wr = W2 + (c0 + cc) * 128 + h2 * 16;
#pragma unroll
            for (int j = 0; j < 16; j++) acc16[j] = fmaf(xv, wr[j], acc16[j]);
        }
    }
    float4* yp = (float4*)(Y3 + (size_t)row * 128 + h2 * 16);
#pragma unroll
    for (int f = 0; f < 4; f++)
        yp[f] = make_float4(acc16[4 * f], acc16[4 * f + 1], acc16[4 * f + 2], acc16[4 * f + 3]);

    __syncthreads();
    if (h2 < 4) {
#pragma unroll
        for (int j = 0; j < 16; j++) buf[rl][h2 * 16 + j] = acc16[j];
    }
    __syncthreads();
    if (t < 128) {
        int c = t & 63;
        float s = 0.0f;
        if (t < 64) { for (int r = 0; r < ROWS; ++r) s += buf[r][c]; }
        else        { for (int r = 0; r < ROWS; ++r) { float v = buf[r][c]; s = fmaf(v, v, s); } }
        part3[blockIdx.x * 256 + t] = s;
    }
    __syncthreads();
    if (h2 >= 4) {
#pragma unroll
        for (int j = 0; j < 16; j++) buf[rl][(h2 - 4) * 16 + j] = acc16[j];
    }
    __syncthreads();
    if (t < 128) {
        int c = t & 63;
        float s = 0.0f;
        if (t < 64) { for (int r = 0; r < ROWS; ++r) s += buf[r][c]; }
        else        { for (int r = 0; r < ROWS; ++r) { float v = buf[r][c]; s = fmaf(v, v, s); } }
        part3[blockIdx.x * 256 + 128 + t] = s;
    }
}

// ---------------- D: stats3 + final normalize in place ----------------
__global__ __launch_bounds__(256) void bnf_kernel(float* __restrict__ Y3,
                                                  const float* __restrict__ g2,
                                                  const float* __restrict__ be2,
                                                  const float* __restrict__ part3) {
    __shared__ float red[256];
    __shared__ float scs[128], shs[128];
    int t = threadIdx.x;
    {
        float s = 0.0f;
#pragma unroll 8
        for (int g = 0; g < NBLK; ++g) s += part3[(size_t)g * 256 + t];
        red[t] = s;
    }
    __syncthreads();
    if (t < 128) {
        int si = (t < 64) ? t : (t + 64);
        float mean = red[si] * (1.0f / BN_);
        float var = red[si + 64] * (1.0f / BN_) - mean * mean;
        float rstd = rsqrtf(var + EPS_);
        float scl = rstd * g2[t];
        scs[t] = scl;
        shs[t] = be2[t] - mean * scl;
    }
    __syncthreads();
    const int total = BN_ * 128 / 4;
    float4* p = (float4*)Y3;
    for (int i = blockIdx.x * 256 + t; i < total; i += 256 * 256) {
        float4 v = p[i];
        int c0 = (i * 4) & 127;
        v.x = fmaxf(0.0f, fmaf(v.x, scs[c0],     shs[c0]));
        v.y = fmaxf(0.0f, fmaf(v.y, scs[c0 + 1], shs[c0 + 1]));
        v.z = fmaxf(0.0f, fmaf(v.z, scs[c0 + 2], shs[c0 + 2]));
        v.w = fmaxf(0.0f, fmaf(v.w, scs[c0 + 3], shs[c0 + 3]));
        p[i] = v;
    }
}

extern "C" void kernel_launch(void* const* d_in, const int* in_sizes, int n_in,
                              void* d_out, int out_size, void* d_ws, size_t ws_size,
                              hipStream_t stream) {
    const float* coords = (const float*)d_in[0];
    const float* feats  = (const float*)d_in[1];
    const float* W1  = (const float*)d_in[3];
    const float* b1  = (const float*)d_in[4];
    const float* g1  = (const float*)d_in[5];
    const float* be1 = (const float*)d_in[6];
    const float* Wa  = (const float*)d_in[7];
    const float* ba  = (const float*)d_in[8];
    const float* ga  = (const float*)d_in[9];
    const float* bea = (const float*)d_in[10];
    const float* W2  = (const float*)d_in[11];
    const float* b2  = (const float*)d_in[12];
    const float* g2  = (const float*)d_in[13];
    const float* be2 = (const float*)d_in[14];

    float* ws = (float*)d_ws;
    float4* coords4 = (float4*)ws;                         // 131072 f
    int*    idxbuf  = (int*)(ws + 131072);                 // BN_*16 ints
    __half* fh      = (__half*)(ws + 131072 + 524288);     // BN_*64 halves
    float*  y1 = ws + 131072 + 524288 + 1048576;           // BN_*64
    float*  x1 = y1 + (size_t)BN_ * 64;
    float*  y2 = x1 + (size_t)BN_ * 64;
    float*  part1 = y2 + (size_t)BN_ * 64;                 // NBLK*128
    float*  part2 = part1 + NBLK * 128;
    float*  part3 = part2 + NBLK * 128;                    // NBLK*256
    float*  y3 = (float*)d_out;

    pack_coords<<<(BN_ + 255) / 256, 256, 0, stream>>>(coords, coords4);
    feats2h<<<BN_ * 64 / 8 / 256, 256, 0, stream>>>(feats, fh);
    knn_2ph<<<B_ * 128, KT_, 0, stream>>>(coords4, idxbuf);

    g1_kernel<<<NBLK, 512, 0, stream>>>(fh, idxbuf, W1, b1, y1, part1);
    m2_kernel<<<NBLK, 512, 0, stream>>>(y1, Wa, ba, g1, be1, part1, x1, y2, part2);
    m3_kernel<<<NBLK, 512, 0, stream>>>(y2, x1, W2, b2, ga, bea, part2, y3, part3);
    bnf_kernel<<<256, 256, 0, stream>>>(y3, g2, be2, part3);
}